// Round 1
// baseline (2967.694 us; speedup 1.0000x reference)
//
#include <hip/hip_runtime.h>
#include <hip/hip_bf16.h>

#define N_NODES 100000
#define N_EDGES 1600000
#define D_IN 128
#define D_OUT 64

// Dense GEMM: out[M, 64] = x[M, K] @ W[K, 64].  Block = 512 threads = 8 rows x 64 cols.
template<int K>
__global__ __launch_bounds__(512) void gemm_nodes(const float* __restrict__ x,
                                                  const float* __restrict__ W,
                                                  float* __restrict__ out, int M) {
    __shared__ float Ws[K * 64];
    __shared__ float xs[8][K];
    const int t = threadIdx.x;
    for (int i = t; i < K * 64; i += 512) Ws[i] = W[i];
    const int row0 = blockIdx.x * 8;
    for (int i = t; i < 8 * K; i += 512) {
        const int r = i / K, k = i % K;
        xs[r][k] = x[(size_t)(row0 + r) * K + k];   // M divisible by 8
    }
    __syncthreads();
    const int col = t & 63;
    const int r = t >> 6;
    float sum = 0.f;
#pragma unroll 16
    for (int k = 0; k < K; ++k) sum += xs[r][k] * Ws[k * 64 + col];
    out[(size_t)(row0 + r) * 64 + col] = sum;
}

// Scatter-add: agg[dst[e]] += w[e] * h[src[e]]  (64 floats / edge; 16 threads / edge)
__global__ __launch_bounds__(256) void scatter_edges(const float* __restrict__ h,
                                                     const int* __restrict__ src,
                                                     const int* __restrict__ dst,
                                                     const float* __restrict__ w,
                                                     float* __restrict__ agg) {
    const int t = blockIdx.x * blockDim.x + threadIdx.x;
    const int e = t >> 4;            // 16 threads per edge
    if (e >= N_EDGES) return;
    const int c = (t & 15) << 2;     // float offset within the 64-wide row
    const int s = src[e];
    const int d = dst[e];
    const float wt = w[e];
    const float4 hv = *(const float4*)(h + (size_t)s * 64 + c);
    float* out = agg + (size_t)d * 64 + c;
    unsafeAtomicAdd(out + 0, wt * hv.x);
    unsafeAtomicAdd(out + 1, wt * hv.y);
    unsafeAtomicAdd(out + 2, wt * hv.z);
    unsafeAtomicAdd(out + 3, wt * hv.w);
}

// In-place: a[i] = relu(a[i] + b[i % 64]), vectorized float4
__global__ __launch_bounds__(256) void bias_relu(float* __restrict__ a,
                                                 const float* __restrict__ b, int n4) {
    const int i = blockIdx.x * blockDim.x + threadIdx.x;
    if (i >= n4) return;
    float4 v = ((float4*)a)[i];
    const int c = (i & 15) << 2;
    v.x = fmaxf(v.x + b[c + 0], 0.f);
    v.y = fmaxf(v.y + b[c + 1], 0.f);
    v.z = fmaxf(v.z + b[c + 2], 0.f);
    v.w = fmaxf(v.w + b[c + 3], 0.f);
    ((float4*)a)[i] = v;
}

extern "C" void kernel_launch(void* const* d_in, const int* in_sizes, int n_in,
                              void* d_out, int out_size, void* d_ws, size_t ws_size,
                              hipStream_t stream) {
    const float* x    = (const float*)d_in[0];          // [100000, 128]
    const int*   eidx = (const int*)d_in[1];            // [2, 1600000]
    const float* mask = (const float*)d_in[2];          // [1600000]
    const float* W1   = (const float*)d_in[3];          // [128, 64]
    const float* b1   = (const float*)d_in[4];          // [64]
    const float* W2   = (const float*)d_in[5];          // [64, 64]
    const float* b2   = (const float*)d_in[6];          // [64]
    float* out = (float*)d_out;                          // [100000, 64]

    const int* src = eidx;
    const int* dst = eidx + N_EDGES;

    const size_t nodeF = (size_t)N_NODES * 64;           // 6.4M floats
    float* hpre = (float*)d_ws;                          // 25.6 MB
    float* hagg = hpre + nodeF;                          // 25.6 MB

    const int n4 = (int)(nodeF / 4);
    const int scatterBlocks = (N_EDGES * 16) / 256;      // 100000
    const int gemmBlocks = N_NODES / 8;                  // 12500

    // ---- Layer 1 ----
    hipMemsetAsync(hagg, 0, nodeF * sizeof(float), stream);
    gemm_nodes<128><<<gemmBlocks, 512, 0, stream>>>(x, W1, hpre, N_NODES);
    scatter_edges<<<scatterBlocks, 256, 0, stream>>>(hpre, src, dst, mask, hagg);
    bias_relu<<<(n4 + 255) / 256, 256, 0, stream>>>(hagg, b1, n4);

    // ---- Layer 2 ----
    hipMemsetAsync(out, 0, nodeF * sizeof(float), stream);
    gemm_nodes<64><<<gemmBlocks, 512, 0, stream>>>(hagg, W2, hpre, N_NODES);
    scatter_edges<<<scatterBlocks, 256, 0, stream>>>(hpre, src, dst, mask, out);
    bias_relu<<<(n4 + 255) / 256, 256, 0, stream>>>(out, b2, n4);
}

// Round 2
// 840.866 us; speedup vs baseline: 3.5293x; 3.5293x over previous
//
#include <hip/hip_runtime.h>
#include <hip/hip_bf16.h>

#define N_NODES 100000
#define N_EDGES 1600000

// ---------- Dense GEMM: out[M, 64] = x[M, K] @ W[K, 64]. 512 thr = 8 rows x 64 cols ----------
template<int K>
__global__ __launch_bounds__(512) void gemm_nodes(const float* __restrict__ x,
                                                  const float* __restrict__ W,
                                                  float* __restrict__ out) {
    __shared__ float Ws[K * 64];
    __shared__ float xs[8][K];
    const int t = threadIdx.x;
    for (int i = t; i < K * 64; i += 512) Ws[i] = W[i];
    const int row0 = blockIdx.x * 8;
    for (int i = t; i < 8 * K; i += 512) {
        const int r = i / K, k = i % K;
        xs[r][k] = x[(size_t)(row0 + r) * K + k];   // N_NODES divisible by 8
    }
    __syncthreads();
    const int col = t & 63;
    const int r = t >> 6;
    float sum = 0.f;
#pragma unroll 16
    for (int k = 0; k < K; ++k) sum += xs[r][k] * Ws[k * 64 + col];
    out[(size_t)(row0 + r) * 64 + col] = sum;
}

// ---------- Counting sort by dst ----------
__global__ __launch_bounds__(256) void hist_dst(const int* __restrict__ dst,
                                                int* __restrict__ cnt) {
    const int e = blockIdx.x * 256 + threadIdx.x;
    if (e < N_EDGES) atomicAdd(&cnt[dst[e]], 1);
}

// one block, 1024 threads: exclusive scan of cnt[0..N_NODES) -> row_ptr, cursor
__global__ __launch_bounds__(1024) void scan_counts(const int* __restrict__ cnt,
                                                    int* __restrict__ row_ptr,
                                                    int* __restrict__ cursor) {
    __shared__ int part[1024];
    const int t = threadIdx.x;
    const int CH = (N_NODES + 1023) / 1024;          // 98
    const int base = t * CH;
    const int end = min(base + CH, N_NODES);
    int s = 0;
    for (int i = base; i < end; ++i) s += cnt[i];
    part[t] = s;
    __syncthreads();
    for (int off = 1; off < 1024; off <<= 1) {
        int v = (t >= off) ? part[t - off] : 0;
        __syncthreads();
        part[t] += v;
        __syncthreads();
    }
    int run = part[t] - s;                            // exclusive prefix of this chunk
    for (int i = base; i < end; ++i) {
        row_ptr[i] = run;
        cursor[i] = run;
        run += cnt[i];
    }
    if (t == 1023) row_ptr[N_NODES] = part[1023];
}

__global__ __launch_bounds__(256) void reorder_edges(const int* __restrict__ src,
                                                     const int* __restrict__ dst,
                                                     const float* __restrict__ w,
                                                     int* __restrict__ cursor,
                                                     int* __restrict__ src_sorted,
                                                     float* __restrict__ w_sorted) {
    const int e = blockIdx.x * 256 + threadIdx.x;
    if (e >= N_EDGES) return;
    const int pos = atomicAdd(&cursor[dst[e]], 1);
    src_sorted[pos] = src[e];
    w_sorted[pos] = w[e];
}

// ---------- Gather-aggregate: one wave per node, lane c = column c; fused bias+relu ----------
__global__ __launch_bounds__(256) void gather_nodes(const float* __restrict__ h,
                                                    const int* __restrict__ row_ptr,
                                                    const int* __restrict__ srcs,
                                                    const float* __restrict__ ws,
                                                    const float* __restrict__ bias,
                                                    float* __restrict__ out) {
    const int node = (blockIdx.x * 256 + threadIdx.x) >> 6;
    if (node >= N_NODES) return;
    const int lane = threadIdx.x & 63;
    const int beg = row_ptr[node];
    const int end = row_ptr[node + 1];
    float acc = 0.f;
    for (int b0 = beg; b0 < end; b0 += 64) {
        const int n = min(64, end - b0);
        int s = 0;
        float wv = 0.f;
        if (lane < n) { s = srcs[b0 + lane]; wv = ws[b0 + lane]; }
        for (int j = 0; j < n; ++j) {
            const int sj = __shfl(s, j);
            const float wj = __shfl(wv, j);
            acc += wj * h[(size_t)sj * 64 + lane];
        }
    }
    out[(size_t)node * 64 + lane] = fmaxf(acc + bias[lane], 0.f);
}

extern "C" void kernel_launch(void* const* d_in, const int* in_sizes, int n_in,
                              void* d_out, int out_size, void* d_ws, size_t ws_size,
                              hipStream_t stream) {
    const float* x    = (const float*)d_in[0];          // [100000, 128]
    const int*   eidx = (const int*)d_in[1];            // [2, 1600000]
    const float* mask = (const float*)d_in[2];          // [1600000]
    const float* W1   = (const float*)d_in[3];          // [128, 64]
    const float* b1   = (const float*)d_in[4];          // [64]
    const float* W2   = (const float*)d_in[5];          // [64, 64]
    const float* b2   = (const float*)d_in[6];          // [64]
    float* out = (float*)d_out;                          // [100000, 64]

    const int* src = eidx;
    const int* dst = eidx + N_EDGES;

    // workspace layout
    const size_t nodeF = (size_t)N_NODES * 64;           // 6.4M floats
    float* hpre       = (float*)d_ws;                    // 25.6 MB
    int*   cnt        = (int*)(hpre + nodeF);            // 100000 ints
    int*   row_ptr    = cnt + N_NODES;                   // 100001 ints
    int*   cursor     = row_ptr + N_NODES + 1;           // 100000 ints
    int*   src_sorted = cursor + N_NODES;                // 1.6M ints
    float* w_sorted   = (float*)(src_sorted + N_EDGES);  // 1.6M floats

    const int gemmBlocks = N_NODES / 8;                  // 12500
    const int edgeBlocks = (N_EDGES + 255) / 256;        // 6250
    const int gatherBlocks = (N_NODES * 64 + 255) / 256; // 25000

    // ---- bucket edges by dst (once; reused by both layers) ----
    hipMemsetAsync(cnt, 0, N_NODES * sizeof(int), stream);
    hist_dst<<<edgeBlocks, 256, 0, stream>>>(dst, cnt);
    scan_counts<<<1, 1024, 0, stream>>>(cnt, row_ptr, cursor);
    reorder_edges<<<edgeBlocks, 256, 0, stream>>>(src, dst, mask, cursor,
                                                  src_sorted, w_sorted);

    // ---- Layer 1: h1 = relu(A @ (x@W1) + b1) ----
    gemm_nodes<128><<<gemmBlocks, 512, 0, stream>>>(x, W1, hpre);
    gather_nodes<<<gatherBlocks, 256, 0, stream>>>(hpre, row_ptr, src_sorted, w_sorted,
                                                   b1, out);

    // ---- Layer 2: h2 = relu(A @ (h1@W2) + b2) ----
    gemm_nodes<64><<<gemmBlocks, 512, 0, stream>>>(out, W2, hpre);
    gather_nodes<<<gatherBlocks, 256, 0, stream>>>(hpre, row_ptr, src_sorted, w_sorted,
                                                   b2, out);
}

// Round 3
// 539.535 us; speedup vs baseline: 5.5005x; 1.5585x over previous
//
#include <hip/hip_runtime.h>
#include <hip/hip_bf16.h>

#define N_NODES 100000
#define N_EDGES 1600000
#define CHUNK 512
#define NCHUNK ((N_NODES + CHUNK - 1) / CHUNK)   // 196

// ---------- Dense GEMM: out[M, 64] = x[M, K] @ W[K, 64]. 512 thr = 8 rows x 64 cols ----------
template<int K>
__global__ __launch_bounds__(512) void gemm_nodes(const float* __restrict__ x,
                                                  const float* __restrict__ W,
                                                  float* __restrict__ out) {
    __shared__ float Ws[K * 64];
    __shared__ float xs[8][K];
    const int t = threadIdx.x;
    for (int i = t; i < K * 64; i += 512) Ws[i] = W[i];
    const int row0 = blockIdx.x * 8;
    for (int i = t; i < 8 * K; i += 512) {
        const int r = i / K, k = i % K;
        xs[r][k] = x[(size_t)(row0 + r) * K + k];   // N_NODES divisible by 8
    }
    __syncthreads();
    const int col = t & 63;
    const int r = t >> 6;
    float sum = 0.f;
#pragma unroll 16
    for (int k = 0; k < K; ++k) sum += xs[r][k] * Ws[k * 64 + col];
    out[(size_t)(row0 + r) * 64 + col] = sum;
}

// ---------- Counting sort by dst ----------
__global__ __launch_bounds__(256) void hist_dst(const int* __restrict__ dst,
                                                int* __restrict__ cnt) {
    const int e = blockIdx.x * 256 + threadIdx.x;
    if (e < N_EDGES) atomicAdd(&cnt[dst[e]], 1);
}

// Phase A: per-chunk sums. 196 blocks x 256 thr, 2 elems/thread.
__global__ __launch_bounds__(256) void scan_chunk_sums(const int* __restrict__ cnt,
                                                       int* __restrict__ chunk_sum) {
    __shared__ int red[256];
    const int t = threadIdx.x;
    const int i0 = blockIdx.x * CHUNK + 2 * t;
    int a = (i0 < N_NODES) ? cnt[i0] : 0;
    int b = (i0 + 1 < N_NODES) ? cnt[i0 + 1] : 0;
    red[t] = a + b;
    __syncthreads();
    for (int off = 128; off > 0; off >>= 1) {
        if (t < off) red[t] += red[t + off];
        __syncthreads();
    }
    if (t == 0) chunk_sum[blockIdx.x] = red[0];
}

// Phase B: one block scans the chunk sums (NCHUNK <= 256) -> exclusive chunk offsets.
__global__ __launch_bounds__(256) void scan_chunk_offsets(const int* __restrict__ chunk_sum,
                                                          int* __restrict__ chunk_off) {
    __shared__ int part[256];
    const int t = threadIdx.x;
    int v = (t < NCHUNK) ? chunk_sum[t] : 0;
    part[t] = v;
    __syncthreads();
    for (int off = 1; off < 256; off <<= 1) {
        int u = (t >= off) ? part[t - off] : 0;
        __syncthreads();
        part[t] += u;
        __syncthreads();
    }
    if (t < NCHUNK) chunk_off[t] = part[t] - v;   // exclusive
}

// Phase C: per-chunk exclusive scan + chunk offset -> row_ptr, cursor.
__global__ __launch_bounds__(256) void scan_write(const int* __restrict__ cnt,
                                                  const int* __restrict__ chunk_off,
                                                  int* __restrict__ row_ptr,
                                                  int* __restrict__ cursor) {
    __shared__ int part[256];
    const int t = threadIdx.x;
    const int i0 = blockIdx.x * CHUNK + 2 * t;
    int a = (i0 < N_NODES) ? cnt[i0] : 0;
    int b = (i0 + 1 < N_NODES) ? cnt[i0 + 1] : 0;
    int pair = a + b;
    part[t] = pair;
    __syncthreads();
    for (int off = 1; off < 256; off <<= 1) {
        int u = (t >= off) ? part[t - off] : 0;
        __syncthreads();
        part[t] += u;
        __syncthreads();
    }
    const int e0 = chunk_off[blockIdx.x] + part[t] - pair;  // exclusive prefix of i0
    const int e1 = e0 + a;
    if (i0 < N_NODES)     { row_ptr[i0] = e0;     cursor[i0] = e0; }
    if (i0 + 1 < N_NODES) { row_ptr[i0 + 1] = e1; cursor[i0 + 1] = e1; }
    if (i0 + 1 == N_NODES - 1) row_ptr[N_NODES] = e1 + b;
    if (i0 == N_NODES - 1)     row_ptr[N_NODES] = e0 + a;
}

__global__ __launch_bounds__(256) void reorder_edges(const int* __restrict__ src,
                                                     const int* __restrict__ dst,
                                                     const float* __restrict__ w,
                                                     int* __restrict__ cursor,
                                                     int* __restrict__ src_sorted,
                                                     float* __restrict__ w_sorted) {
    const int e = blockIdx.x * 256 + threadIdx.x;
    if (e >= N_EDGES) return;
    const int pos = atomicAdd(&cursor[dst[e]], 1);
    src_sorted[pos] = src[e];
    w_sorted[pos] = w[e];
}

// ---------- Gather-aggregate: one wave per node, lane c = column c; fused bias+relu ----------
__global__ __launch_bounds__(256) void gather_nodes(const float* __restrict__ h,
                                                    const int* __restrict__ row_ptr,
                                                    const int* __restrict__ srcs,
                                                    const float* __restrict__ ws,
                                                    const float* __restrict__ bias,
                                                    float* __restrict__ out) {
    const int node = (blockIdx.x * 256 + threadIdx.x) >> 6;
    if (node >= N_NODES) return;
    const int lane = threadIdx.x & 63;
    const int beg = row_ptr[node];
    const int end = row_ptr[node + 1];
    float acc0 = 0.f, acc1 = 0.f, acc2 = 0.f, acc3 = 0.f;
    for (int b0 = beg; b0 < end; b0 += 64) {
        const int n = min(64, end - b0);
        int s = 0;
        float wv = 0.f;
        if (lane < n) { s = srcs[b0 + lane]; wv = ws[b0 + lane]; }
        int j = 0;
        for (; j + 3 < n; j += 4) {
            const int s0 = __shfl(s, j);     const float w0 = __shfl(wv, j);
            const int s1 = __shfl(s, j + 1); const float w1 = __shfl(wv, j + 1);
            const int s2 = __shfl(s, j + 2); const float w2 = __shfl(wv, j + 2);
            const int s3 = __shfl(s, j + 3); const float w3 = __shfl(wv, j + 3);
            acc0 += w0 * h[(size_t)s0 * 64 + lane];
            acc1 += w1 * h[(size_t)s1 * 64 + lane];
            acc2 += w2 * h[(size_t)s2 * 64 + lane];
            acc3 += w3 * h[(size_t)s3 * 64 + lane];
        }
        for (; j < n; ++j) {
            const int sj = __shfl(s, j);
            const float wj = __shfl(wv, j);
            acc0 += wj * h[(size_t)sj * 64 + lane];
        }
    }
    const float acc = (acc0 + acc1) + (acc2 + acc3);
    out[(size_t)node * 64 + lane] = fmaxf(acc + bias[lane], 0.f);
}

extern "C" void kernel_launch(void* const* d_in, const int* in_sizes, int n_in,
                              void* d_out, int out_size, void* d_ws, size_t ws_size,
                              hipStream_t stream) {
    const float* x    = (const float*)d_in[0];          // [100000, 128]
    const int*   eidx = (const int*)d_in[1];            // [2, 1600000]
    const float* mask = (const float*)d_in[2];          // [1600000]
    const float* W1   = (const float*)d_in[3];          // [128, 64]
    const float* b1   = (const float*)d_in[4];          // [64]
    const float* W2   = (const float*)d_in[5];          // [64, 64]
    const float* b2   = (const float*)d_in[6];          // [64]
    float* out = (float*)d_out;                          // [100000, 64]

    const int* src = eidx;
    const int* dst = eidx + N_EDGES;

    // workspace layout
    const size_t nodeF = (size_t)N_NODES * 64;           // 6.4M floats
    float* hpre       = (float*)d_ws;                    // 25.6 MB
    int*   cnt        = (int*)(hpre + nodeF);            // 100000 ints
    int*   row_ptr    = cnt + N_NODES;                   // 100001 ints
    int*   cursor     = row_ptr + N_NODES + 1;           // 100000 ints
    int*   chunk_sum  = cursor + N_NODES;                // 196 ints
    int*   chunk_off  = chunk_sum + NCHUNK;              // 196 ints
    int*   src_sorted = chunk_off + NCHUNK;              // 1.6M ints
    float* w_sorted   = (float*)(src_sorted + N_EDGES);  // 1.6M floats

    const int gemmBlocks = N_NODES / 8;                  // 12500
    const int edgeBlocks = (N_EDGES + 255) / 256;        // 6250
    const int gatherBlocks = (N_NODES * 64 + 255) / 256; // 25000

    // ---- bucket edges by dst (once; reused by both layers) ----
    hipMemsetAsync(cnt, 0, N_NODES * sizeof(int), stream);
    hist_dst<<<edgeBlocks, 256, 0, stream>>>(dst, cnt);
    scan_chunk_sums<<<NCHUNK, 256, 0, stream>>>(cnt, chunk_sum);
    scan_chunk_offsets<<<1, 256, 0, stream>>>(chunk_sum, chunk_off);
    scan_write<<<NCHUNK, 256, 0, stream>>>(cnt, chunk_off, row_ptr, cursor);
    reorder_edges<<<edgeBlocks, 256, 0, stream>>>(src, dst, mask, cursor,
                                                  src_sorted, w_sorted);

    // ---- Layer 1: h1 = relu(A @ (x@W1) + b1) ----
    gemm_nodes<128><<<gemmBlocks, 512, 0, stream>>>(x, W1, hpre);
    gather_nodes<<<gatherBlocks, 256, 0, stream>>>(hpre, row_ptr, src_sorted, w_sorted,
                                                   b1, out);

    // ---- Layer 2: h2 = relu(A @ (h1@W2) + b2) ----
    gemm_nodes<64><<<gemmBlocks, 512, 0, stream>>>(out, W2, hpre);
    gather_nodes<<<gatherBlocks, 256, 0, stream>>>(hpre, row_ptr, src_sorted, w_sorted,
                                                   b2, out);
}

// Round 4
// 455.417 us; speedup vs baseline: 6.5164x; 1.1847x over previous
//
#include <hip/hip_runtime.h>
#include <hip/hip_bf16.h>

#define N_NODES 100000
#define N_EDGES 1600000
#define CHUNK 512
#define NCHUNK ((N_NODES + CHUNK - 1) / CHUNK)   // 196

// ---------- Dense GEMM: out[M,64] = x[M,K] @ W[K,64].
// 512 thr = 16 col-quads x 32 rows; b128 LDS reads; 3125 blocks. ----------
template<int K>
__global__ __launch_bounds__(512) void gemm_nodes(const float* __restrict__ x,
                                                  const float* __restrict__ W,
                                                  float* __restrict__ out) {
    __shared__ float Ws[K][64];        // same layout as W, contiguous copy
    __shared__ float xs[32][K + 4];    // +4 pad keeps 16B align, breaks bank stride
    const int t = threadIdx.x;
    {
        const float4* W4 = (const float4*)W;
        for (int i = t; i < K * 16; i += 512) ((float4*)&Ws[0][0])[i] = W4[i];
    }
    const int row0 = blockIdx.x * 32;
    {
        const float4* x4 = (const float4*)(x + (size_t)row0 * K);
        for (int i = t; i < 32 * K / 4; i += 512) {
            const int r = (i * 4) / K, k = (i * 4) % K;
            *(float4*)&xs[r][k] = x4[i];
        }
    }
    __syncthreads();
    const int c4 = (t & 15) * 4;
    const int r = t >> 4;
    float ax = 0.f, ay = 0.f, az = 0.f, aw = 0.f;
#pragma unroll
    for (int k = 0; k < K; k += 4) {
        const float4 xv = *(const float4*)&xs[r][k];
        const float4 w0 = *(const float4*)&Ws[k][c4];
        const float4 w1 = *(const float4*)&Ws[k + 1][c4];
        const float4 w2 = *(const float4*)&Ws[k + 2][c4];
        const float4 w3 = *(const float4*)&Ws[k + 3][c4];
        ax += xv.x * w0.x + xv.y * w1.x + xv.z * w2.x + xv.w * w3.x;
        ay += xv.x * w0.y + xv.y * w1.y + xv.z * w2.y + xv.w * w3.y;
        az += xv.x * w0.z + xv.y * w1.z + xv.z * w2.z + xv.w * w3.z;
        aw += xv.x * w0.w + xv.y * w1.w + xv.z * w2.w + xv.w * w3.w;
    }
    float4 acc = {ax, ay, az, aw};
    *(float4*)&out[(size_t)(row0 + r) * 64 + c4] = acc;
}

// ---------- Counting sort by dst ----------
__global__ __launch_bounds__(256) void hist_dst(const int* __restrict__ dst,
                                                int* __restrict__ cnt) {
    const int e = blockIdx.x * 256 + threadIdx.x;
    if (e < N_EDGES) atomicAdd(&cnt[dst[e]], 1);
}

__global__ __launch_bounds__(256) void scan_chunk_sums(const int* __restrict__ cnt,
                                                       int* __restrict__ chunk_sum) {
    __shared__ int red[256];
    const int t = threadIdx.x;
    const int i0 = blockIdx.x * CHUNK + 2 * t;
    int a = (i0 < N_NODES) ? cnt[i0] : 0;
    int b = (i0 + 1 < N_NODES) ? cnt[i0 + 1] : 0;
    red[t] = a + b;
    __syncthreads();
    for (int off = 128; off > 0; off >>= 1) {
        if (t < off) red[t] += red[t + off];
        __syncthreads();
    }
    if (t == 0) chunk_sum[blockIdx.x] = red[0];
}

__global__ __launch_bounds__(256) void scan_chunk_offsets(const int* __restrict__ chunk_sum,
                                                          int* __restrict__ chunk_off) {
    __shared__ int part[256];
    const int t = threadIdx.x;
    int v = (t < NCHUNK) ? chunk_sum[t] : 0;
    part[t] = v;
    __syncthreads();
    for (int off = 1; off < 256; off <<= 1) {
        int u = (t >= off) ? part[t - off] : 0;
        __syncthreads();
        part[t] += u;
        __syncthreads();
    }
    if (t < NCHUNK) chunk_off[t] = part[t] - v;   // exclusive
}

__global__ __launch_bounds__(256) void scan_write(const int* __restrict__ cnt,
                                                  const int* __restrict__ chunk_off,
                                                  int* __restrict__ row_ptr,
                                                  int* __restrict__ cursor) {
    __shared__ int part[256];
    const int t = threadIdx.x;
    const int i0 = blockIdx.x * CHUNK + 2 * t;
    int a = (i0 < N_NODES) ? cnt[i0] : 0;
    int b = (i0 + 1 < N_NODES) ? cnt[i0 + 1] : 0;
    int pair = a + b;
    part[t] = pair;
    __syncthreads();
    for (int off = 1; off < 256; off <<= 1) {
        int u = (t >= off) ? part[t - off] : 0;
        __syncthreads();
        part[t] += u;
        __syncthreads();
    }
    const int e0 = chunk_off[blockIdx.x] + part[t] - pair;
    const int e1 = e0 + a;
    if (i0 < N_NODES)     { row_ptr[i0] = e0;     cursor[i0] = e0; }
    if (i0 + 1 < N_NODES) { row_ptr[i0 + 1] = e1; cursor[i0 + 1] = e1; }
    if (i0 + 1 == N_NODES - 1) row_ptr[N_NODES] = e1 + b;
    if (i0 == N_NODES - 1)     row_ptr[N_NODES] = e0 + a;
}

// single packed 8B scattered store per edge
__global__ __launch_bounds__(256) void reorder_edges(const int* __restrict__ src,
                                                     const int* __restrict__ dst,
                                                     const float* __restrict__ w,
                                                     int* __restrict__ cursor,
                                                     int2* __restrict__ edge_sorted) {
    const int e = blockIdx.x * 256 + threadIdx.x;
    if (e >= N_EDGES) return;
    const int pos = atomicAdd(&cursor[dst[e]], 1);
    int2 ev;
    ev.x = src[e];
    ev.y = __float_as_int(w[e]);
    edge_sorted[pos] = ev;
}

// ---------- Gather-aggregate: one wave per node, lane c = column c; fused bias+relu ----------
__global__ __launch_bounds__(256) void gather_nodes(const float* __restrict__ h,
                                                    const int* __restrict__ row_ptr,
                                                    const int2* __restrict__ edges,
                                                    const float* __restrict__ bias,
                                                    float* __restrict__ out) {
    const int node = (blockIdx.x * 256 + threadIdx.x) >> 6;
    if (node >= N_NODES) return;
    const int lane = threadIdx.x & 63;
    const int beg = row_ptr[node];
    const int end = row_ptr[node + 1];
    float acc0 = 0.f, acc1 = 0.f, acc2 = 0.f, acc3 = 0.f;
    for (int b0 = beg; b0 < end; b0 += 64) {
        const int n = min(64, end - b0);
        int s = 0;
        float wv = 0.f;
        if (lane < n) {
            const int2 ev = edges[b0 + lane];
            s = ev.x;
            wv = __int_as_float(ev.y);
        }
        int j = 0;
        for (; j + 3 < n; j += 4) {
            const int s0 = __shfl(s, j);     const float w0 = __shfl(wv, j);
            const int s1 = __shfl(s, j + 1); const float w1 = __shfl(wv, j + 1);
            const int s2 = __shfl(s, j + 2); const float w2 = __shfl(wv, j + 2);
            const int s3 = __shfl(s, j + 3); const float w3 = __shfl(wv, j + 3);
            acc0 += w0 * h[(size_t)s0 * 64 + lane];
            acc1 += w1 * h[(size_t)s1 * 64 + lane];
            acc2 += w2 * h[(size_t)s2 * 64 + lane];
            acc3 += w3 * h[(size_t)s3 * 64 + lane];
        }
        for (; j < n; ++j) {
            const int sj = __shfl(s, j);
            const float wj = __shfl(wv, j);
            acc0 += wj * h[(size_t)sj * 64 + lane];
        }
    }
    const float acc = (acc0 + acc1) + (acc2 + acc3);
    out[(size_t)node * 64 + lane] = fmaxf(acc + bias[lane], 0.f);
}

extern "C" void kernel_launch(void* const* d_in, const int* in_sizes, int n_in,
                              void* d_out, int out_size, void* d_ws, size_t ws_size,
                              hipStream_t stream) {
    const float* x    = (const float*)d_in[0];          // [100000, 128]
    const int*   eidx = (const int*)d_in[1];            // [2, 1600000]
    const float* mask = (const float*)d_in[2];          // [1600000]
    const float* W1   = (const float*)d_in[3];          // [128, 64]
    const float* b1   = (const float*)d_in[4];          // [64]
    const float* W2   = (const float*)d_in[5];          // [64, 64]
    const float* b2   = (const float*)d_in[6];          // [64]
    float* out = (float*)d_out;                          // [100000, 64]

    const int* src = eidx;
    const int* dst = eidx + N_EDGES;

    // workspace layout (8B-aligned first)
    const size_t nodeF = (size_t)N_NODES * 64;           // 6.4M floats
    float* hpre        = (float*)d_ws;                   // 25.6 MB
    int2*  edge_sorted = (int2*)(hpre + nodeF);          // 12.8 MB, 8B-aligned
    int*   cnt         = (int*)(edge_sorted + N_EDGES);  // 100000 ints
    int*   row_ptr     = cnt + N_NODES;                  // 100001 ints
    int*   cursor      = row_ptr + N_NODES + 1;          // 100000 ints
    int*   chunk_sum   = cursor + N_NODES;               // 196 ints
    int*   chunk_off   = chunk_sum + NCHUNK;             // 196 ints

    const int gemmBlocks = N_NODES / 32;                 // 3125
    const int edgeBlocks = (N_EDGES + 255) / 256;        // 6250
    const int gatherBlocks = (N_NODES * 64 + 255) / 256; // 25000

    // ---- bucket edges by dst (once; reused by both layers) ----
    hipMemsetAsync(cnt, 0, N_NODES * sizeof(int), stream);
    hist_dst<<<edgeBlocks, 256, 0, stream>>>(dst, cnt);
    scan_chunk_sums<<<NCHUNK, 256, 0, stream>>>(cnt, chunk_sum);
    scan_chunk_offsets<<<1, 256, 0, stream>>>(chunk_sum, chunk_off);
    scan_write<<<NCHUNK, 256, 0, stream>>>(cnt, chunk_off, row_ptr, cursor);
    reorder_edges<<<edgeBlocks, 256, 0, stream>>>(src, dst, mask, cursor, edge_sorted);

    // ---- Layer 1: h1 = relu(A @ (x@W1) + b1) ----
    gemm_nodes<128><<<gemmBlocks, 512, 0, stream>>>(x, W1, hpre);
    gather_nodes<<<gatherBlocks, 256, 0, stream>>>(hpre, row_ptr, edge_sorted, b1, out);

    // ---- Layer 2: h2 = relu(A @ (h1@W2) + b2) ----
    gemm_nodes<64><<<gemmBlocks, 512, 0, stream>>>(out, W2, hpre);
    gather_nodes<<<gatherBlocks, 256, 0, stream>>>(hpre, row_ptr, edge_sorted, b2, out);
}

// Round 5
// 347.448 us; speedup vs baseline: 8.5414x; 1.3108x over previous
//
#include <hip/hip_runtime.h>
#include <hip/hip_bf16.h>

#define N_NODES 100000
#define N_EDGES 1600000
#define NBUCKET 782                 // ceil(100000 / 128) coarse buckets (dst >> 7)
#define NBLK 200                    // edge chunks
#define CHUNK_E 8000                // 200 * 8000 = 1.6M exactly
#define T2 (NBUCKET * NBLK)         // 156400 (bucket-major (bucket, block) matrix)
#define NCH2 ((T2 + 511) / 512)     // 306

// ---------- Dense GEMM: out[M,64] = x[M,K] @ W[K,64]. 512 thr = 16 col-quads x 32 rows ----------
template<int K>
__global__ __launch_bounds__(512) void gemm_nodes(const float* __restrict__ x,
                                                  const float* __restrict__ W,
                                                  float* __restrict__ out) {
    __shared__ float Ws[K][64];
    __shared__ float xs[32][K + 4];
    const int t = threadIdx.x;
    {
        const float4* W4 = (const float4*)W;
        for (int i = t; i < K * 16; i += 512) ((float4*)&Ws[0][0])[i] = W4[i];
    }
    const int row0 = blockIdx.x * 32;
    {
        const float4* x4 = (const float4*)(x + (size_t)row0 * K);
        for (int i = t; i < 32 * K / 4; i += 512) {
            const int r = (i * 4) / K, k = (i * 4) % K;
            *(float4*)&xs[r][k] = x4[i];
        }
    }
    __syncthreads();
    const int c4 = (t & 15) * 4;
    const int r = t >> 4;
    float ax = 0.f, ay = 0.f, az = 0.f, aw = 0.f;
#pragma unroll
    for (int k = 0; k < K; k += 4) {
        const float4 xv = *(const float4*)&xs[r][k];
        const float4 w0 = *(const float4*)&Ws[k][c4];
        const float4 w1 = *(const float4*)&Ws[k + 1][c4];
        const float4 w2 = *(const float4*)&Ws[k + 2][c4];
        const float4 w3 = *(const float4*)&Ws[k + 3][c4];
        ax += xv.x * w0.x + xv.y * w1.x + xv.z * w2.x + xv.w * w3.x;
        ay += xv.x * w0.y + xv.y * w1.y + xv.z * w2.y + xv.w * w3.y;
        az += xv.x * w0.z + xv.y * w1.z + xv.z * w2.z + xv.w * w3.z;
        aw += xv.x * w0.w + xv.y * w1.w + xv.z * w2.w + xv.w * w3.w;
    }
    float4 acc = {ax, ay, az, aw};
    *(float4*)&out[(size_t)(row0 + r) * 64 + c4] = acc;
}

// ---------- S1: per-(block,bucket) coarse histogram ----------
__global__ __launch_bounds__(256) void s1_hist(const int* __restrict__ dst,
                                               int* __restrict__ bh) {
    __shared__ int hist[NBUCKET];
    const int t = threadIdx.x;
    for (int i = t; i < NBUCKET; i += 256) hist[i] = 0;
    __syncthreads();
    const int e0 = blockIdx.x * CHUNK_E;
    for (int i = t; i < CHUNK_E; i += 256)
        atomicAdd(&hist[dst[e0 + i] >> 7], 1);
    __syncthreads();
    for (int i = t; i < NBUCKET; i += 256)
        bh[i * NBLK + blockIdx.x] = hist[i];
}

// ---------- S2: 3-phase exclusive scan of bh[T2] -> bh_ex ----------
__global__ __launch_bounds__(256) void scan_sums(const int* __restrict__ v,
                                                 int* __restrict__ csum, int n) {
    __shared__ int red[256];
    const int t = threadIdx.x;
    const int i0 = blockIdx.x * 512 + 2 * t;
    int a = (i0 < n) ? v[i0] : 0;
    int b = (i0 + 1 < n) ? v[i0 + 1] : 0;
    red[t] = a + b;
    __syncthreads();
    for (int off = 128; off > 0; off >>= 1) {
        if (t < off) red[t] += red[t + off];
        __syncthreads();
    }
    if (t == 0) csum[blockIdx.x] = red[0];
}

__global__ __launch_bounds__(512) void scan_off(const int* __restrict__ csum,
                                                int* __restrict__ coff, int nch) {
    __shared__ int part[512];
    const int t = threadIdx.x;
    int v = (t < nch) ? csum[t] : 0;
    part[t] = v;
    __syncthreads();
    for (int off = 1; off < 512; off <<= 1) {
        int u = (t >= off) ? part[t - off] : 0;
        __syncthreads();
        part[t] += u;
        __syncthreads();
    }
    if (t < nch) coff[t] = part[t] - v;   // exclusive
}

__global__ __launch_bounds__(256) void scan_apply(const int* __restrict__ v,
                                                  const int* __restrict__ coff,
                                                  int* __restrict__ vex, int n) {
    __shared__ int part[256];
    const int t = threadIdx.x;
    const int i0 = blockIdx.x * 512 + 2 * t;
    int a = (i0 < n) ? v[i0] : 0;
    int b = (i0 + 1 < n) ? v[i0 + 1] : 0;
    int pair = a + b;
    part[t] = pair;
    __syncthreads();
    for (int off = 1; off < 256; off <<= 1) {
        int u = (t >= off) ? part[t - off] : 0;
        __syncthreads();
        part[t] += u;
        __syncthreads();
    }
    const int e0 = coff[blockIdx.x] + part[t] - pair;
    if (i0 < n)     vex[i0] = e0;
    if (i0 + 1 < n) vex[i0 + 1] = e0 + a;
}

// ---------- S3: scatter edges into coarse buckets (runs of ~10 per (block,bucket)) ----------
__global__ __launch_bounds__(256) void s3_scatter(const int* __restrict__ src,
                                                  const int* __restrict__ dst,
                                                  const float* __restrict__ w,
                                                  const int* __restrict__ bh_ex,
                                                  int2* __restrict__ coarse) {
    __shared__ int cur[NBUCKET];
    const int t = threadIdx.x;
    for (int i = t; i < NBUCKET; i += 256) cur[i] = bh_ex[i * NBLK + blockIdx.x];
    __syncthreads();
    const int e0 = blockIdx.x * CHUNK_E;
    for (int i = t; i < CHUNK_E; i += 256) {
        const int e = e0 + i;
        const int d = dst[e];
        const int pos = atomicAdd(&cur[d >> 7], 1);
        int2 ev;
        ev.x = src[e] | ((d & 127) << 17);   // src < 2^17
        ev.y = __float_as_int(w[e]);
        coarse[pos] = ev;
    }
}

// ---------- S4: per-bucket fine sort (128 nodes) + row_ptr; writes L2-hot 16KB region ----------
__global__ __launch_bounds__(256) void s4_fine(const int2* __restrict__ coarse,
                                               const int* __restrict__ bh_ex,
                                               int2* __restrict__ edge_sorted,
                                               int* __restrict__ row_ptr) {
    __shared__ int hist[128];
    __shared__ int part[128];
    __shared__ int cursor[128];
    const int b = blockIdx.x;
    const int t = threadIdx.x;
    const int beg = bh_ex[b * NBLK];
    const int end = (b + 1 < NBUCKET) ? bh_ex[(b + 1) * NBLK] : N_EDGES;
    if (t < 128) hist[t] = 0;
    __syncthreads();
    for (int i = beg + t; i < end; i += 256)
        atomicAdd(&hist[(coarse[i].x >> 17) & 127], 1);
    __syncthreads();
    if (t < 128) part[t] = hist[t];
    __syncthreads();
    for (int off = 1; off < 128; off <<= 1) {
        int u = 0;
        if (t < 128 && t >= off) u = part[t - off];
        __syncthreads();
        if (t < 128) part[t] += u;
        __syncthreads();
    }
    if (t < 128) {
        const int excl = beg + part[t] - hist[t];
        cursor[t] = excl;
        const int node = b * 128 + t;
        if (node < N_NODES) row_ptr[node] = excl;
    }
    if (b == NBUCKET - 1 && t == 0) row_ptr[N_NODES] = N_EDGES;
    __syncthreads();
    for (int i = beg + t; i < end; i += 256) {
        int2 ev = coarse[i];
        const int f = (ev.x >> 17) & 127;
        const int pos = atomicAdd(&cursor[f], 1);
        ev.x &= 0x1FFFF;
        edge_sorted[pos] = ev;
    }
}

// ---------- Gather-aggregate: one wave per node, lane = column; fused bias+relu ----------
__global__ __launch_bounds__(256) void gather_nodes(const float* __restrict__ h,
                                                    const int* __restrict__ row_ptr,
                                                    const int2* __restrict__ edges,
                                                    const float* __restrict__ bias,
                                                    float* __restrict__ out) {
    const int node = (blockIdx.x * 256 + threadIdx.x) >> 6;
    if (node >= N_NODES) return;
    const int lane = threadIdx.x & 63;
    const int beg = row_ptr[node];
    const int end = row_ptr[node + 1];
    float acc[8];
#pragma unroll
    for (int q = 0; q < 8; ++q) acc[q] = 0.f;
    for (int b0 = beg; b0 < end; b0 += 64) {
        const int n = min(64, end - b0);
        int s = 0;
        float wv = 0.f;
        if (lane < n) {
            const int2 ev = edges[b0 + lane];
            s = ev.x;
            wv = __int_as_float(ev.y);
        }
        int j = 0;
        for (; j + 7 < n; j += 8) {
            int ss[8]; float ww[8];
#pragma unroll
            for (int q = 0; q < 8; ++q) { ss[q] = __shfl(s, j + q); ww[q] = __shfl(wv, j + q); }
#pragma unroll
            for (int q = 0; q < 8; ++q) acc[q] += ww[q] * h[(size_t)ss[q] * 64 + lane];
        }
        if (j + 3 < n) {
            int ss[4]; float ww[4];
#pragma unroll
            for (int q = 0; q < 4; ++q) { ss[q] = __shfl(s, j + q); ww[q] = __shfl(wv, j + q); }
#pragma unroll
            for (int q = 0; q < 4; ++q) acc[q] += ww[q] * h[(size_t)ss[q] * 64 + lane];
            j += 4;
        }
        for (; j < n; ++j) {
            const int sj = __shfl(s, j);
            const float wj = __shfl(wv, j);
            acc[0] += wj * h[(size_t)sj * 64 + lane];
        }
    }
    const float a = ((acc[0] + acc[1]) + (acc[2] + acc[3])) +
                    ((acc[4] + acc[5]) + (acc[6] + acc[7]));
    out[(size_t)node * 64 + lane] = fmaxf(a + bias[lane], 0.f);
}

extern "C" void kernel_launch(void* const* d_in, const int* in_sizes, int n_in,
                              void* d_out, int out_size, void* d_ws, size_t ws_size,
                              hipStream_t stream) {
    const float* x    = (const float*)d_in[0];          // [100000, 128]
    const int*   eidx = (const int*)d_in[1];            // [2, 1600000]
    const float* mask = (const float*)d_in[2];          // [1600000]
    const float* W1   = (const float*)d_in[3];          // [128, 64]
    const float* b1   = (const float*)d_in[4];          // [64]
    const float* W2   = (const float*)d_in[5];          // [64, 64]
    const float* b2   = (const float*)d_in[6];          // [64]
    float* out = (float*)d_out;                          // [100000, 64]

    const int* src = eidx;
    const int* dst = eidx + N_EDGES;

    // workspace layout (8B-aligned blocks first)
    const size_t nodeF = (size_t)N_NODES * 64;           // 6.4M floats
    float* hpre        = (float*)d_ws;                   // 25.6 MB
    int2*  edge_sorted = (int2*)(hpre + nodeF);          // 12.8 MB
    int2*  coarse      = edge_sorted + N_EDGES;          // 12.8 MB
    int*   bh          = (int*)(coarse + N_EDGES);       // 156400 ints
    int*   bh_ex       = bh + T2;                        // 156400 ints
    int*   csum2       = bh_ex + T2;                     // 306 ints
    int*   coff2       = csum2 + NCH2;                   // 306 ints
    int*   row_ptr     = coff2 + NCH2;                   // 100001 ints

    const int gemmBlocks = N_NODES / 32;                 // 3125
    const int gatherBlocks = (N_NODES * 64 + 255) / 256; // 25000

    // ---- two-level counting sort by dst (once; reused by both layers) ----
    s1_hist<<<NBLK, 256, 0, stream>>>(dst, bh);
    scan_sums<<<NCH2, 256, 0, stream>>>(bh, csum2, T2);
    scan_off<<<1, 512, 0, stream>>>(csum2, coff2, NCH2);
    scan_apply<<<NCH2, 256, 0, stream>>>(bh, coff2, bh_ex, T2);
    s3_scatter<<<NBLK, 256, 0, stream>>>(src, dst, mask, bh_ex, coarse);
    s4_fine<<<NBUCKET, 256, 0, stream>>>(coarse, bh_ex, edge_sorted, row_ptr);

    // ---- Layer 1: h1 = relu(A @ (x@W1) + b1) ----
    gemm_nodes<128><<<gemmBlocks, 512, 0, stream>>>(x, W1, hpre);
    gather_nodes<<<gatherBlocks, 256, 0, stream>>>(hpre, row_ptr, edge_sorted, b1, out);

    // ---- Layer 2: h2 = relu(A @ (h1@W2) + b2) ----
    gemm_nodes<64><<<gemmBlocks, 512, 0, stream>>>(out, W2, hpre);
    gather_nodes<<<gatherBlocks, 256, 0, stream>>>(hpre, row_ptr, edge_sorted, b2, out);
}

// Round 6
// 321.922 us; speedup vs baseline: 9.2187x; 1.0793x over previous
//
#include <hip/hip_runtime.h>
#include <hip/hip_bf16.h>

#define N_NODES 100000
#define N_EDGES 1600000
#define NBUCKET 782                 // ceil(100000 / 128) coarse buckets (dst >> 7)
#define NBLK 200                    // edge chunks
#define CHUNK_E 8000                // 200 * 8000 = 1.6M exactly
#define T2 (NBUCKET * NBLK)         // 156400 (bucket-major (bucket, block) matrix)
#define NCH2 ((T2 + 511) / 512)     // 306

static __device__ __forceinline__ unsigned pack_bf2(float a, float b) {
    __hip_bfloat162 p = __float22bfloat162_rn(make_float2(a, b));
    return *reinterpret_cast<unsigned*>(&p);
}
static __device__ __forceinline__ float2 bf2_to_f2(unsigned u) {
    __hip_bfloat162 p = *reinterpret_cast<__hip_bfloat162*>(&u);
    return __bfloat1622float2(p);
}

// ---------- Dense GEMM: out_bf16[M,64] = in[M,K] @ W[K,64]. 512 thr = 16 col-quads x 32 rows ----------
template<int K>
__global__ __launch_bounds__(512) void gemm_nodes(const float* __restrict__ x,
                                                  const float* __restrict__ W,
                                                  unsigned* __restrict__ out) {  // bf162 pairs
    __shared__ float Ws[K][64];
    __shared__ float xs[32][K + 4];
    const int t = threadIdx.x;
    {
        const float4* W4 = (const float4*)W;
        for (int i = t; i < K * 16; i += 512) ((float4*)&Ws[0][0])[i] = W4[i];
    }
    const int row0 = blockIdx.x * 32;
    {
        const float4* x4 = (const float4*)(x + (size_t)row0 * K);
        for (int i = t; i < 32 * K / 4; i += 512) {
            const int r = (i * 4) / K, k = (i * 4) % K;
            *(float4*)&xs[r][k] = x4[i];
        }
    }
    __syncthreads();
    const int c4 = (t & 15) * 4;
    const int r = t >> 4;
    float ax = 0.f, ay = 0.f, az = 0.f, aw = 0.f;
#pragma unroll
    for (int k = 0; k < K; k += 4) {
        const float4 xv = *(const float4*)&xs[r][k];
        const float4 w0 = *(const float4*)&Ws[k][c4];
        const float4 w1 = *(const float4*)&Ws[k + 1][c4];
        const float4 w2 = *(const float4*)&Ws[k + 2][c4];
        const float4 w3 = *(const float4*)&Ws[k + 3][c4];
        ax += xv.x * w0.x + xv.y * w1.x + xv.z * w2.x + xv.w * w3.x;
        ay += xv.x * w0.y + xv.y * w1.y + xv.z * w2.y + xv.w * w3.y;
        az += xv.x * w0.z + xv.y * w1.z + xv.z * w2.z + xv.w * w3.z;
        aw += xv.x * w0.w + xv.y * w1.w + xv.z * w2.w + xv.w * w3.w;
    }
    uint2 o;
    o.x = pack_bf2(ax, ay);
    o.y = pack_bf2(az, aw);
    *(uint2*)&out[(size_t)(row0 + r) * 32 + c4 / 2] = o;
}

// ---------- S1: per-(block,bucket) coarse histogram ----------
__global__ __launch_bounds__(256) void s1_hist(const int* __restrict__ dst,
                                               int* __restrict__ bh) {
    __shared__ int hist[NBUCKET];
    const int t = threadIdx.x;
    for (int i = t; i < NBUCKET; i += 256) hist[i] = 0;
    __syncthreads();
    const int e0 = blockIdx.x * CHUNK_E;
    for (int i = t; i < CHUNK_E; i += 256)
        atomicAdd(&hist[dst[e0 + i] >> 7], 1);
    __syncthreads();
    for (int i = t; i < NBUCKET; i += 256)
        bh[i * NBLK + blockIdx.x] = hist[i];
}

// ---------- S2: 3-phase exclusive scan of bh[T2] -> bh_ex ----------
__global__ __launch_bounds__(256) void scan_sums(const int* __restrict__ v,
                                                 int* __restrict__ csum, int n) {
    __shared__ int red[256];
    const int t = threadIdx.x;
    const int i0 = blockIdx.x * 512 + 2 * t;
    int a = (i0 < n) ? v[i0] : 0;
    int b = (i0 + 1 < n) ? v[i0 + 1] : 0;
    red[t] = a + b;
    __syncthreads();
    for (int off = 128; off > 0; off >>= 1) {
        if (t < off) red[t] += red[t + off];
        __syncthreads();
    }
    if (t == 0) csum[blockIdx.x] = red[0];
}

__global__ __launch_bounds__(512) void scan_off(const int* __restrict__ csum,
                                                int* __restrict__ coff, int nch) {
    __shared__ int part[512];
    const int t = threadIdx.x;
    int v = (t < nch) ? csum[t] : 0;
    part[t] = v;
    __syncthreads();
    for (int off = 1; off < 512; off <<= 1) {
        int u = (t >= off) ? part[t - off] : 0;
        __syncthreads();
        part[t] += u;
        __syncthreads();
    }
    if (t < nch) coff[t] = part[t] - v;   // exclusive
}

__global__ __launch_bounds__(256) void scan_apply(const int* __restrict__ v,
                                                  const int* __restrict__ coff,
                                                  int* __restrict__ vex, int n) {
    __shared__ int part[256];
    const int t = threadIdx.x;
    const int i0 = blockIdx.x * 512 + 2 * t;
    int a = (i0 < n) ? v[i0] : 0;
    int b = (i0 + 1 < n) ? v[i0 + 1] : 0;
    int pair = a + b;
    part[t] = pair;
    __syncthreads();
    for (int off = 1; off < 256; off <<= 1) {
        int u = (t >= off) ? part[t - off] : 0;
        __syncthreads();
        part[t] += u;
        __syncthreads();
    }
    const int e0 = coff[blockIdx.x] + part[t] - pair;
    if (i0 < n)     vex[i0] = e0;
    if (i0 + 1 < n) vex[i0 + 1] = e0 + a;
}

// ---------- S3: scatter edges into coarse buckets (runs of ~10 per (block,bucket)) ----------
__global__ __launch_bounds__(256) void s3_scatter(const int* __restrict__ src,
                                                  const int* __restrict__ dst,
                                                  const float* __restrict__ w,
                                                  const int* __restrict__ bh_ex,
                                                  int2* __restrict__ coarse) {
    __shared__ int cur[NBUCKET];
    const int t = threadIdx.x;
    for (int i = t; i < NBUCKET; i += 256) cur[i] = bh_ex[i * NBLK + blockIdx.x];
    __syncthreads();
    const int e0 = blockIdx.x * CHUNK_E;
    for (int i = t; i < CHUNK_E; i += 256) {
        const int e = e0 + i;
        const int d = dst[e];
        const int pos = atomicAdd(&cur[d >> 7], 1);
        int2 ev;
        ev.x = src[e] | ((d & 127) << 17);   // src < 2^17
        ev.y = __float_as_int(w[e]);
        coarse[pos] = ev;
    }
}

// ---------- S4: per-bucket fine sort (128 nodes) + row_ptr ----------
__global__ __launch_bounds__(256) void s4_fine(const int2* __restrict__ coarse,
                                               const int* __restrict__ bh_ex,
                                               int2* __restrict__ edge_sorted,
                                               int* __restrict__ row_ptr) {
    __shared__ int hist[128];
    __shared__ int part[128];
    __shared__ int cursor[128];
    const int b = blockIdx.x;
    const int t = threadIdx.x;
    const int beg = bh_ex[b * NBLK];
    const int end = (b + 1 < NBUCKET) ? bh_ex[(b + 1) * NBLK] : N_EDGES;
    if (t < 128) hist[t] = 0;
    __syncthreads();
    for (int i = beg + t; i < end; i += 256)
        atomicAdd(&hist[(coarse[i].x >> 17) & 127], 1);
    __syncthreads();
    if (t < 128) part[t] = hist[t];
    __syncthreads();
    for (int off = 1; off < 128; off <<= 1) {
        int u = 0;
        if (t < 128 && t >= off) u = part[t - off];
        __syncthreads();
        if (t < 128) part[t] += u;
        __syncthreads();
    }
    if (t < 128) {
        const int excl = beg + part[t] - hist[t];
        cursor[t] = excl;
        const int node = b * 128 + t;
        if (node < N_NODES) row_ptr[node] = excl;
    }
    if (b == NBUCKET - 1 && t == 0) row_ptr[N_NODES] = N_EDGES;
    __syncthreads();
    for (int i = beg + t; i < end; i += 256) {
        int2 ev = coarse[i];
        const int f = (ev.x >> 17) & 127;
        const int pos = atomicAdd(&cursor[f], 1);
        ev.x &= 0x1FFFF;
        edge_sorted[pos] = ev;
    }
}

// ---------- Gather-aggregate (bf16 h): half-wave per edge, lane = (col-pair, half) ----------
__global__ __launch_bounds__(256) void gather_nodes_bf(const unsigned* __restrict__ h, // bf162[N][32]
                                                       const int* __restrict__ row_ptr,
                                                       const int2* __restrict__ edges,
                                                       const float* __restrict__ bias,
                                                       float* __restrict__ out) {
    const int node = (blockIdx.x * 256 + threadIdx.x) >> 6;
    if (node >= N_NODES) return;
    const int lane = threadIdx.x & 63;
    const int c = lane & 31;          // column pair: cols {2c, 2c+1}
    const int half = lane >> 5;       // which edge of each pair this lane handles
    const int beg = row_ptr[node];
    const int end = row_ptr[node + 1];
    float ax[4] = {0.f, 0.f, 0.f, 0.f};
    float ay[4] = {0.f, 0.f, 0.f, 0.f};
    for (int b0 = beg; b0 < end; b0 += 64) {
        const int n = min(64, end - b0);
        int s = 0;
        float wv = 0.f;
        if (lane < n) {
            const int2 ev = edges[b0 + lane];
            s = ev.x;
            wv = __int_as_float(ev.y);
        }
        const int pairs = n >> 1;
        int p = 0;
        for (; p + 3 < pairs; p += 4) {
            int ss[4]; float ww[4];
#pragma unroll
            for (int q = 0; q < 4; ++q) {
                const int j = 2 * (p + q) + half;
                ss[q] = __shfl(s, j);
                ww[q] = __shfl(wv, j);
            }
#pragma unroll
            for (int q = 0; q < 4; ++q) {
                const float2 f = bf2_to_f2(h[(size_t)ss[q] * 32 + c]);
                ax[q] += ww[q] * f.x;
                ay[q] += ww[q] * f.y;
            }
        }
        for (; p < pairs; ++p) {
            const int j = 2 * p + half;
            const int sj = __shfl(s, j);
            const float wj = __shfl(wv, j);
            const float2 f = bf2_to_f2(h[(size_t)sj * 32 + c]);
            ax[0] += wj * f.x;
            ay[0] += wj * f.y;
        }
        if (n & 1) {                       // odd tail: low half only
            const int sj = __shfl(s, n - 1);
            float wj = __shfl(wv, n - 1);
            if (half) wj = 0.f;
            const float2 f = bf2_to_f2(h[(size_t)sj * 32 + c]);
            ax[0] += wj * f.x;
            ay[0] += wj * f.y;
        }
    }
    float sx = (ax[0] + ax[1]) + (ax[2] + ax[3]);
    float sy = (ay[0] + ay[1]) + (ay[2] + ay[3]);
    sx += __shfl_xor(sx, 32);
    sy += __shfl_xor(sy, 32);
    if (half == 0) {
        float2 o;
        o.x = fmaxf(sx + bias[2 * c], 0.f);
        o.y = fmaxf(sy + bias[2 * c + 1], 0.f);
        *(float2*)&out[(size_t)node * 64 + 2 * c] = o;
    }
}

extern "C" void kernel_launch(void* const* d_in, const int* in_sizes, int n_in,
                              void* d_out, int out_size, void* d_ws, size_t ws_size,
                              hipStream_t stream) {
    const float* x    = (const float*)d_in[0];          // [100000, 128]
    const int*   eidx = (const int*)d_in[1];            // [2, 1600000]
    const float* mask = (const float*)d_in[2];          // [1600000]
    const float* W1   = (const float*)d_in[3];          // [128, 64]
    const float* b1   = (const float*)d_in[4];          // [64]
    const float* W2   = (const float*)d_in[5];          // [64, 64]
    const float* b2   = (const float*)d_in[6];          // [64]
    float* out = (float*)d_out;                          // [100000, 64]

    const int* src = eidx;
    const int* dst = eidx + N_EDGES;

    // workspace layout (8B-aligned blocks first)
    unsigned* hpre     = (unsigned*)d_ws;                // bf16 h: 100000*32 uints = 12.8 MB
    int2*  edge_sorted = (int2*)(hpre + (size_t)N_NODES * 32);  // 12.8 MB
    int2*  coarse      = edge_sorted + N_EDGES;          // 12.8 MB
    int*   bh          = (int*)(coarse + N_EDGES);       // 156400 ints
    int*   bh_ex       = bh + T2;                        // 156400 ints
    int*   csum2       = bh_ex + T2;                     // 306 ints
    int*   coff2       = csum2 + NCH2;                   // 306 ints
    int*   row_ptr     = coff2 + NCH2;                   // 100001 ints

    const int gemmBlocks = N_NODES / 32;                 // 3125
    const int gatherBlocks = (N_NODES * 64 + 255) / 256; // 25000

    // ---- two-level counting sort by dst (once; reused by both layers) ----
    s1_hist<<<NBLK, 256, 0, stream>>>(dst, bh);
    scan_sums<<<NCH2, 256, 0, stream>>>(bh, csum2, T2);
    scan_off<<<1, 512, 0, stream>>>(csum2, coff2, NCH2);
    scan_apply<<<NCH2, 256, 0, stream>>>(bh, coff2, bh_ex, T2);
    s3_scatter<<<NBLK, 256, 0, stream>>>(src, dst, mask, bh_ex, coarse);
    s4_fine<<<NBUCKET, 256, 0, stream>>>(coarse, bh_ex, edge_sorted, row_ptr);

    // ---- Layer 1: h1 = relu(A @ bf16(x@W1) + b1) ----
    gemm_nodes<128><<<gemmBlocks, 512, 0, stream>>>(x, W1, hpre);
    gather_nodes_bf<<<gatherBlocks, 256, 0, stream>>>(hpre, row_ptr, edge_sorted, b1, out);

    // ---- Layer 2: h2 = relu(A @ bf16(h1@W2) + b2) ----
    gemm_nodes<64><<<gemmBlocks, 512, 0, stream>>>(out, W2, hpre);
    gather_nodes_bf<<<gatherBlocks, 256, 0, stream>>>(hpre, row_ptr, edge_sorted, b2, out);
}

// Round 7
// 281.705 us; speedup vs baseline: 10.5347x; 1.1428x over previous
//
#include <hip/hip_runtime.h>
#include <hip/hip_bf16.h>

#define N_NODES 100000
#define N_EDGES 1600000
#define NBUCKET 782                 // ceil(100000 / 128) coarse buckets (dst >> 7)
#define NBLK 200                    // edge chunks
#define CHUNK_E 8000                // 200 * 8000 = 1.6M exactly
#define T2 (NBUCKET * NBLK)         // 156400
#define NCH2 ((T2 + 511) / 512)     // 306

typedef short v8s __attribute__((ext_vector_type(8)));
typedef float v4f __attribute__((ext_vector_type(4)));

static __device__ __forceinline__ unsigned pack_bf2(float a, float b) {
    __hip_bfloat162 p = __float22bfloat162_rn(make_float2(a, b));
    return *reinterpret_cast<unsigned*>(&p);
}
static __device__ __forceinline__ float2 bf2_to_f2(unsigned u) {
    __hip_bfloat162 p = *reinterpret_cast<__hip_bfloat162*>(&u);
    return __bfloat1622float2(p);
}

// ---------- prep: transpose W -> Wt[n][k] bf16 (once, tiny) ----------
__global__ __launch_bounds__(256) void prep_w(const float* __restrict__ W1,
                                              const float* __restrict__ W2,
                                              short* __restrict__ wt1,   // [64][128]
                                              short* __restrict__ wt2) { // [64][64]
    const int t = threadIdx.x;
    for (int i = t; i < 64 * 128; i += 256) {
        const int c = i >> 7, k = i & 127;
        wt1[i] = (short)(pack_bf2(W1[k * 64 + c], 0.f) & 0xFFFF);
    }
    for (int i = t; i < 64 * 64; i += 256) {
        const int c = i >> 6, k = i & 63;
        wt2[i] = (short)(pack_bf2(W2[k * 64 + c], 0.f) & 0xFFFF);
    }
}

// ---------- MFMA GEMM: outp_bf16[M,64] = in[M,K] @ W[K,64] ----------
// Block: 256 thr = 4 waves, 64 nodes x 64 cols. D-layout: col(lane&15)=node,
// row(quad*4+reg)=output col -> 8B packed stores per tile.
template<int K, bool IN_BF>
__global__ __launch_bounds__(256) void gemm_mfma(const void* __restrict__ in,
                                                 const short* __restrict__ wt,  // [64][K] bf16
                                                 unsigned* __restrict__ outp) { // bf162 [node][32]
    __shared__ unsigned xs[64][K / 2 + 4];
    __shared__ unsigned ws[64][K / 2 + 4];
    const int t = threadIdx.x;
    const int row0 = blockIdx.x * 64;
    {   // stage Wt (already bf16, row-major [64][K])
        const uint2* g = (const uint2*)wt;
        for (int i = t; i < 64 * K / 4; i += 256) {
            const int r = i / (K / 4), cu = i % (K / 4);
            ((uint2*)&ws[r][0])[cu] = g[i];
        }
    }
    if (IN_BF) {
        const uint2* g = (const uint2*)in;
        for (int i = t; i < 64 * K / 4; i += 256) {
            const int r = i / (K / 4), cu = i % (K / 4);
            const int row = row0 + r;
            uint2 v = make_uint2(0u, 0u);
            if (row < N_NODES) v = g[(size_t)row * (K / 4) + cu];
            ((uint2*)&xs[r][0])[cu] = v;
        }
    } else {
        const float4* g = (const float4*)in;
        for (int i = t; i < 64 * K / 4; i += 256) {
            const int r = i / (K / 4), cu = i % (K / 4);
            const int row = row0 + r;
            uint2 v = make_uint2(0u, 0u);
            if (row < N_NODES) {
                float4 f = g[(size_t)row * (K / 4) + cu];
                v.x = pack_bf2(f.x, f.y);
                v.y = pack_bf2(f.z, f.w);
            }
            ((uint2*)&xs[r][0])[cu] = v;
        }
    }
    __syncthreads();
    const int w = t >> 6;
    const int lane = t & 63;
    const int l15 = lane & 15;
    const int quad = lane >> 4;
    v4f acc[4];
#pragma unroll
    for (int tt = 0; tt < 4; ++tt) acc[tt] = (v4f){0.f, 0.f, 0.f, 0.f};
#pragma unroll
    for (int k0 = 0; k0 < K; k0 += 32) {
        const int ku = k0 / 2 + quad * 4;
        const v8s xb = *(const v8s*)&xs[w * 16 + l15][ku];   // B: n=node
#pragma unroll
        for (int tt = 0; tt < 4; ++tt) {
            const v8s wa = *(const v8s*)&ws[16 * tt + l15][ku];  // A: m=out col
            acc[tt] = __builtin_amdgcn_mfma_f32_16x16x32_bf16(wa, xb, acc[tt], 0, 0, 0);
        }
    }
    const int node = row0 + w * 16 + l15;
    if (node < N_NODES) {
#pragma unroll
        for (int tt = 0; tt < 4; ++tt) {
            uint2 o;
            o.x = pack_bf2(acc[tt][0], acc[tt][1]);
            o.y = pack_bf2(acc[tt][2], acc[tt][3]);
            *(uint2*)&outp[(size_t)node * 32 + 8 * tt + 2 * quad] = o;
        }
    }
}

// ---------- S1: per-(block,bucket) coarse histogram ----------
__global__ __launch_bounds__(256) void s1_hist(const int* __restrict__ dst,
                                               int* __restrict__ bh) {
    __shared__ int hist[NBUCKET];
    const int t = threadIdx.x;
    for (int i = t; i < NBUCKET; i += 256) hist[i] = 0;
    __syncthreads();
    const int e0 = blockIdx.x * CHUNK_E;
    for (int i = t; i < CHUNK_E; i += 256)
        atomicAdd(&hist[dst[e0 + i] >> 7], 1);
    __syncthreads();
    for (int i = t; i < NBUCKET; i += 256)
        bh[i * NBLK + blockIdx.x] = hist[i];
}

// ---------- S2: 3-phase exclusive scan of bh[T2] -> bh_ex ----------
__global__ __launch_bounds__(256) void scan_sums(const int* __restrict__ v,
                                                 int* __restrict__ csum, int n) {
    __shared__ int red[256];
    const int t = threadIdx.x;
    const int i0 = blockIdx.x * 512 + 2 * t;
    int a = (i0 < n) ? v[i0] : 0;
    int b = (i0 + 1 < n) ? v[i0 + 1] : 0;
    red[t] = a + b;
    __syncthreads();
    for (int off = 128; off > 0; off >>= 1) {
        if (t < off) red[t] += red[t + off];
        __syncthreads();
    }
    if (t == 0) csum[blockIdx.x] = red[0];
}

__global__ __launch_bounds__(512) void scan_off(const int* __restrict__ csum,
                                                int* __restrict__ coff, int nch) {
    __shared__ int part[512];
    const int t = threadIdx.x;
    int v = (t < nch) ? csum[t] : 0;
    part[t] = v;
    __syncthreads();
    for (int off = 1; off < 512; off <<= 1) {
        int u = (t >= off) ? part[t - off] : 0;
        __syncthreads();
        part[t] += u;
        __syncthreads();
    }
    if (t < nch) coff[t] = part[t] - v;   // exclusive
}

__global__ __launch_bounds__(256) void scan_apply(const int* __restrict__ v,
                                                  const int* __restrict__ coff,
                                                  int* __restrict__ vex, int n) {
    __shared__ int part[256];
    const int t = threadIdx.x;
    const int i0 = blockIdx.x * 512 + 2 * t;
    int a = (i0 < n) ? v[i0] : 0;
    int b = (i0 + 1 < n) ? v[i0 + 1] : 0;
    int pair = a + b;
    part[t] = pair;
    __syncthreads();
    for (int off = 1; off < 256; off <<= 1) {
        int u = (t >= off) ? part[t - off] : 0;
        __syncthreads();
        part[t] += u;
        __syncthreads();
    }
    const int e0 = coff[blockIdx.x] + part[t] - pair;
    if (i0 < n)     vex[i0] = e0;
    if (i0 + 1 < n) vex[i0 + 1] = e0 + a;
}

// ---------- S3: scatter edges into coarse buckets ----------
__global__ __launch_bounds__(256) void s3_scatter(const int* __restrict__ src,
                                                  const int* __restrict__ dst,
                                                  const float* __restrict__ w,
                                                  const int* __restrict__ bh_ex,
                                                  int2* __restrict__ coarse) {
    __shared__ int cur[NBUCKET];
    const int t = threadIdx.x;
    for (int i = t; i < NBUCKET; i += 256) cur[i] = bh_ex[i * NBLK + blockIdx.x];
    __syncthreads();
    const int e0 = blockIdx.x * CHUNK_E;
    for (int i = t; i < CHUNK_E; i += 256) {
        const int e = e0 + i;
        const int d = dst[e];
        const int pos = atomicAdd(&cur[d >> 7], 1);
        int2 ev;
        ev.x = src[e] | ((d & 127) << 17);   // src < 2^17
        ev.y = __float_as_int(w[e]);
        coarse[pos] = ev;
    }
}

// ---------- S4: per-bucket fine sort (128 nodes) + row_ptr ----------
__global__ __launch_bounds__(256) void s4_fine(const int2* __restrict__ coarse,
                                               const int* __restrict__ bh_ex,
                                               int2* __restrict__ edge_sorted,
                                               int* __restrict__ row_ptr) {
    __shared__ int hist[128];
    __shared__ int part[128];
    __shared__ int cursor[128];
    const int b = blockIdx.x;
    const int t = threadIdx.x;
    const int beg = bh_ex[b * NBLK];
    const int end = (b + 1 < NBUCKET) ? bh_ex[(b + 1) * NBLK] : N_EDGES;
    if (t < 128) hist[t] = 0;
    __syncthreads();
    for (int i = beg + t; i < end; i += 256)
        atomicAdd(&hist[(coarse[i].x >> 17) & 127], 1);
    __syncthreads();
    if (t < 128) part[t] = hist[t];
    __syncthreads();
    for (int off = 1; off < 128; off <<= 1) {
        int u = 0;
        if (t < 128 && t >= off) u = part[t - off];
        __syncthreads();
        if (t < 128) part[t] += u;
        __syncthreads();
    }
    if (t < 128) {
        const int excl = beg + part[t] - hist[t];
        cursor[t] = excl;
        const int node = b * 128 + t;
        if (node < N_NODES) row_ptr[node] = excl;
    }
    if (b == NBUCKET - 1 && t == 0) row_ptr[N_NODES] = N_EDGES;
    __syncthreads();
    for (int i = beg + t; i < end; i += 256) {
        int2 ev = coarse[i];
        const int f = (ev.x >> 17) & 127;
        const int pos = atomicAdd(&cursor[f], 1);
        ev.x &= 0x1FFFF;
        edge_sorted[pos] = ev;
    }
}

// ---------- Gather-aggregate (bf16 h): half-wave per edge ----------
// OUT_BF: write bf162 (feeds next gemm); else fp32 to d_out.
template<bool OUT_BF>
__global__ __launch_bounds__(256) void gather_nodes_bf(const unsigned* __restrict__ h, // bf162[N][32]
                                                       const int* __restrict__ row_ptr,
                                                       const int2* __restrict__ edges,
                                                       const float* __restrict__ bias,
                                                       void* __restrict__ outp) {
    const int node = (blockIdx.x * 256 + threadIdx.x) >> 6;
    if (node >= N_NODES) return;
    const int lane = threadIdx.x & 63;
    const int c = lane & 31;          // column pair: cols {2c, 2c+1}
    const int half = lane >> 5;
    const int beg = row_ptr[node];
    const int end = row_ptr[node + 1];
    float ax[4] = {0.f, 0.f, 0.f, 0.f};
    float ay[4] = {0.f, 0.f, 0.f, 0.f};
    for (int b0 = beg; b0 < end; b0 += 64) {
        const int n = min(64, end - b0);
        int s = 0;
        float wv = 0.f;
        if (lane < n) {
            const int2 ev = edges[b0 + lane];
            s = ev.x;
            wv = __int_as_float(ev.y);
        }
        const int pairs = n >> 1;
        int p = 0;
        for (; p + 3 < pairs; p += 4) {
            int ss[4]; float ww[4];
#pragma unroll
            for (int q = 0; q < 4; ++q) {
                const int j = 2 * (p + q) + half;
                ss[q] = __shfl(s, j);
                ww[q] = __shfl(wv, j);
            }
#pragma unroll
            for (int q = 0; q < 4; ++q) {
                const float2 f = bf2_to_f2(h[(size_t)ss[q] * 32 + c]);
                ax[q] += ww[q] * f.x;
                ay[q] += ww[q] * f.y;
            }
        }
        for (; p < pairs; ++p) {
            const int j = 2 * p + half;
            const int sj = __shfl(s, j);
            const float wj = __shfl(wv, j);
            const float2 f = bf2_to_f2(h[(size_t)sj * 32 + c]);
            ax[0] += wj * f.x;
            ay[0] += wj * f.y;
        }
        if (n & 1) {
            const int sj = __shfl(s, n - 1);
            float wj = __shfl(wv, n - 1);
            if (half) wj = 0.f;
            const float2 f = bf2_to_f2(h[(size_t)sj * 32 + c]);
            ax[0] += wj * f.x;
            ay[0] += wj * f.y;
        }
    }
    float sx = (ax[0] + ax[1]) + (ax[2] + ax[3]);
    float sy = (ay[0] + ay[1]) + (ay[2] + ay[3]);
    sx += __shfl_xor(sx, 32);
    sy += __shfl_xor(sy, 32);
    if (half == 0) {
        const float rx = fmaxf(sx + bias[2 * c], 0.f);
        const float ry = fmaxf(sy + bias[2 * c + 1], 0.f);
        if (OUT_BF) {
            ((unsigned*)outp)[(size_t)node * 32 + c] = pack_bf2(rx, ry);
        } else {
            float2 o; o.x = rx; o.y = ry;
            *(float2*)&((float*)outp)[(size_t)node * 64 + 2 * c] = o;
        }
    }
}

extern "C" void kernel_launch(void* const* d_in, const int* in_sizes, int n_in,
                              void* d_out, int out_size, void* d_ws, size_t ws_size,
                              hipStream_t stream) {
    const float* x    = (const float*)d_in[0];          // [100000, 128]
    const int*   eidx = (const int*)d_in[1];            // [2, 1600000]
    const float* mask = (const float*)d_in[2];          // [1600000]
    const float* W1   = (const float*)d_in[3];          // [128, 64]
    const float* b1   = (const float*)d_in[4];          // [64]
    const float* W2   = (const float*)d_in[5];          // [64, 64]
    const float* b2   = (const float*)d_in[6];          // [64]
    float* out = (float*)d_out;                          // [100000, 64]

    const int* src = eidx;
    const int* dst = eidx + N_EDGES;

    // workspace layout
    unsigned* hpre     = (unsigned*)d_ws;                      // 12.8 MB bf16 h
    int2*  edge_sorted = (int2*)(hpre + (size_t)N_NODES * 32); // 12.8 MB
    int2*  coarse      = edge_sorted + N_EDGES;                // 12.8 MB (dead after s4)
    unsigned* h1bf     = (unsigned*)coarse;                    // alias: layer-1 output bf16
    int*   bh          = (int*)(coarse + N_EDGES);             // 156400 ints
    int*   bh_ex       = bh + T2;
    int*   csum2       = bh_ex + T2;
    int*   coff2       = csum2 + NCH2;
    int*   row_ptr     = coff2 + NCH2;                         // 100001 ints
    short* wt1         = (short*)(row_ptr + N_NODES + 1);      // 16 KB
    short* wt2         = wt1 + 64 * 128;                       // 8 KB

    const int gemmBlocks = (N_NODES + 63) / 64;          // 1563
    const int gatherBlocks = (N_NODES * 64 + 255) / 256; // 25000

    prep_w<<<1, 256, 0, stream>>>(W1, W2, wt1, wt2);

    // ---- two-level counting sort by dst (once; reused by both layers) ----
    s1_hist<<<NBLK, 256, 0, stream>>>(dst, bh);
    scan_sums<<<NCH2, 256, 0, stream>>>(bh, csum2, T2);
    scan_off<<<1, 512, 0, stream>>>(csum2, coff2, NCH2);
    scan_apply<<<NCH2, 256, 0, stream>>>(bh, coff2, bh_ex, T2);
    s3_scatter<<<NBLK, 256, 0, stream>>>(src, dst, mask, bh_ex, coarse);
    s4_fine<<<NBUCKET, 256, 0, stream>>>(coarse, bh_ex, edge_sorted, row_ptr);

    // ---- Layer 1: h1 = relu(A @ bf16(x@W1) + b1), stored bf16 ----
    gemm_mfma<128, false><<<gemmBlocks, 256, 0, stream>>>(x, wt1, hpre);
    gather_nodes_bf<true><<<gatherBlocks, 256, 0, stream>>>(hpre, row_ptr, edge_sorted,
                                                            b1, h1bf);

    // ---- Layer 2: h2 = relu(A @ bf16(h1@W2) + b2), fp32 out ----
    gemm_mfma<64, true><<<gemmBlocks, 256, 0, stream>>>(h1bf, wt2, hpre);
    gather_nodes_bf<false><<<gatherBlocks, 256, 0, stream>>>(hpre, row_ptr, edge_sorted,
                                                             b2, out);
}